// Round 1
// 476.730 us; speedup vs baseline: 1.0066x; 1.0066x over previous
//
#include <hip/hip_runtime.h>

// Problem: B=8, Tq=2048, Tk=2048, D=1024 (all fp32 in/out)
//   scores  = Q @ K^T            [B,Tq,Tk]
//   weights = softmax(scores)    (output 1, at d_out + 16777216)
//   context = weights @ K        (output 0, at d_out)
//
// ws layout (96 MB):
//   phase 1:  Qh f16 [B][Tq][D] @ 0       (32 MB)
//             Kh f16 [B][Tk][D] @ 32 MB   (32 MB)
//             Kt f16 [B][D][Tk] @ 64 MB   (32 MB)
//   phase 2 (after QK GEMM, Qh/Kh dead):
//             Wh f16 [B][Tq][Tk] @ 0      (64 MB)   <- written by softmax
//
// GEMM: 256x256 tile, 8 waves (2Mx4N), BK=64, 32x32x16 f16 MFMA,
// 8-phase-per-2-K-tiles schedule with counted vmcnt(6) (T2+T3+T4+T5 stack):
// per tile 4 phases {ra*ca, ra*cb, rb*cb, rb*ca}; one 16KB half-tile staged
// per phase, 3 half-tiles in flight; vmcnt only at tile boundaries.
// LDS regions: A-half h = rows with bit6==h of the 256-row tile (so each
// wave_m strip contributes 64 rows); B-half h = rows with bit5==h (32 cols
// per wave_n strip). XOR-8 chunk swizzle applied on the *global source*
// (global_load_lds dest is lane-linear) and on the read side.

typedef _Float16 f16;
typedef _Float16 half4 __attribute__((ext_vector_type(4)));
typedef _Float16 half8 __attribute__((ext_vector_type(8)));
typedef float floatx16 __attribute__((ext_vector_type(16)));

__device__ __forceinline__ void gl2lds16(const void* g, void* l) {
    __builtin_amdgcn_global_load_lds(
        (const __attribute__((address_space(1))) unsigned int*)g,
        (__attribute__((address_space(3))) unsigned int*)l,
        16, 0, 0);
}

#define MFMA(a, b, c) __builtin_amdgcn_mfma_f32_32x32x16_f16((a), (b), (c), 0, 0, 0)

// ---- fp32 -> fp16 convert ----
__global__ __launch_bounds__(256) void cvt_f32_f16(const float* __restrict__ src,
                                                   f16* __restrict__ dst, int n4) {
    int i = blockIdx.x * 256 + threadIdx.x;
    if (i >= n4) return;
    float4 v = ((const float4*)src)[i];
    half4 h;
    h[0] = (f16)v.x; h[1] = (f16)v.y; h[2] = (f16)v.z; h[3] = (f16)v.w;
    ((half4*)dst)[i] = h;
}

// ---- K: fp32 -> fp16 row-major copy + transposed copy (64x64 tiles) ----
__global__ __launch_bounds__(256) void k_cvt_transpose(const float* __restrict__ K,
                                                       f16* __restrict__ Kh,
                                                       f16* __restrict__ Kt) {
    __shared__ f16 tile[64][72];                  // +8 f16 pad
    const int b  = blockIdx.z;
    const int k0 = blockIdx.y * 64;               // Tk tile
    const int d0 = blockIdx.x * 64;               // D tile
    const float* src = K + (size_t)b * 2048 * 1024;
    f16* khb = Kh + (size_t)b * 2048 * 1024;
    f16* ktb = Kt + (size_t)b * 1024 * 2048;
    const int r  = threadIdx.x >> 4;              // 0..15
    const int c4 = (threadIdx.x & 15) * 4;        // 0..60
    #pragma unroll
    for (int it = 0; it < 4; it++) {
        int kr = it * 16 + r;
        float4 v = *(const float4*)&src[(size_t)(k0 + kr) * 1024 + d0 + c4];
        half4 h;
        h[0] = (f16)v.x; h[1] = (f16)v.y; h[2] = (f16)v.z; h[3] = (f16)v.w;
        *(half4*)&khb[(size_t)(k0 + kr) * 1024 + d0 + c4] = h;
        *(half4*)&tile[kr][c4] = h;
    }
    __syncthreads();
    #pragma unroll
    for (int it = 0; it < 4; it++) {
        int dr = it * 16 + r;
        half4 h;
        h[0] = tile[c4 + 0][dr]; h[1] = tile[c4 + 1][dr];
        h[2] = tile[c4 + 2][dr]; h[3] = tile[c4 + 3][dr];
        *(half4*)&ktb[(size_t)(d0 + dr) * 2048 + k0 + c4] = h;
    }
}

// ---- 8-phase 256x256 bt-GEMM: C[M,N] = A[M,K_] * B[N,K_]^T, fp32 out ----
// grid dim3(8, nM*nN), x = batch -> XCD. 512 threads = 8 waves (2M x 4N).
__global__ __launch_bounds__(512) void gemm_bt8(const f16* __restrict__ Amat,
                                                const f16* __restrict__ Bmat,
                                                float* __restrict__ C,
                                                int K_, int N, int nN,
                                                long sA, long sB, long sC) {
    // [parity][half-region][128 rows x 64 f16] ; 64 KB + 64 KB = 128 KiB
    __shared__ __align__(16) f16 LA[2][2][8192];
    __shared__ __align__(16) f16 LB[2][2][8192];
    const int tid  = threadIdx.x;
    const int lane = tid & 63;
    const int wave = tid >> 6;                    // 0..7
    const int wm   = wave >> 2;                   // 0..1 (row strip of 128)
    const int wn   = wave & 3;                    // 0..3 (col strip of 64)
    const int bz   = blockIdx.x;                  // batch -> XCD
    const int tileM = (blockIdx.y / nN) * 256;
    const int tileN = (blockIdx.y % nN) * 256;
    const f16* Ab = Amat + (size_t)bz * sA;
    const f16* Bb = Bmat + (size_t)bz * sB;
    float* Cb = C + (size_t)bz * sC;
    const int NT = K_ >> 6;                       // K-tiles of 64

    // ---- staging precompute (thread t stages chunks t and t+512 of each
    // 16KB half-tile; chunk c: lds_row=c>>3, cc=c&7, source k-chunk = cc^(row&7))
    const int r0  = tid >> 3;                     // 0..63 (lds_row of chunk #tid)
    const int gcc = (tid & 7) ^ (r0 & 7);
    // A half-tile h covers global rows tileM + h*64 + [0,64) and +128.
    const f16* sAp = Ab + (size_t)(tileM + r0) * K_ + gcc * 8;
    // B half-tile h covers global rows tileN + h*32 + strip*64, strips 0..3.
    const f16* sBp = Bb + (size_t)(tileN + (r0 & 31) + (r0 >> 5) * 64) * K_ + gcc * 8;

    // ---- read-side indices
    const int r31 = lane & 31;                    // row within 32-frag
    const int kh  = lane >> 5;                    // k-half selector
    const int sw  = lane & 7;                     // XOR key (== lds_row&7)

    floatx16 acc[4][2];                           // [m-frag 0..3][n-frag 0..1]
    #pragma unroll
    for (int f = 0; f < 4; f++)
        #pragma unroll
        for (int g = 0; g < 2; g++)
            #pragma unroll
            for (int r = 0; r < 16; r++) acc[f][g][r] = 0.f;

    auto STAGE_A = [&](int par, int h, int T) {
        const f16* s = sAp + (size_t)(h * 64) * K_ + T * 64;
        f16* d = &LA[par][h][tid * 8];
        gl2lds16(s, d);
        gl2lds16(s + (size_t)128 * K_, d + 4096);
    };
    auto STAGE_B = [&](int par, int h, int T) {
        const f16* s = sBp + (size_t)(h * 32) * K_ + T * 64;
        f16* d = &LB[par][h][tid * 8];
        gl2lds16(s, d);
        gl2lds16(s + (size_t)128 * K_, d + 4096);
    };
    // A m-frag f (0..3): region f>>1, lds_row = (f&1)*32 + r31 + wm*64
    auto LDA = [&](int par, int f, int ks) -> half8 {
        int lr = ((f & 1) << 5) + r31 + (wm << 6);
        int pc = ((ks << 1) + kh) ^ sw;
        return *(const half8*)&LA[par][f >> 1][lr * 64 + pc * 8];
    };
    // B n-frag g (0..1): region g, lds_row = wn*32 + r31
    auto LDB = [&](int par, int g, int ks) -> half8 {
        int lr = (wn << 5) + r31;
        int pc = ((ks << 1) + kh) ^ sw;
        return *(const half8*)&LB[par][g][lr * 64 + pc * 8];
    };

    // ---- prologue: tile0 {A0,B0,A1,B1} + tile1 {A0,B0,A1}; B1(tile1) comes
    // at T=0 p0. vmcnt(6) -> all of tile0 landed, tile1's 3 half-tiles in flight.
    STAGE_A(0, 0, 0); STAGE_B(0, 0, 0); STAGE_A(0, 1, 0); STAGE_B(0, 1, 0);
    STAGE_A(1, 0, 1); STAGE_B(1, 0, 1); STAGE_A(1, 1, 1);
    asm volatile("s_waitcnt vmcnt(6)" ::: "memory");
    __builtin_amdgcn_s_barrier();

    half8 af[2][4], bfa[4], bfb[4];
    for (int T = 0; T < NT; ++T) {
        const int par = T & 1, nxt = par ^ 1;
        // ---------- phase 0: ra*ca (12 ds_reads; stage B1 of T+1) ----------
        #pragma unroll
        for (int ks = 0; ks < 4; ks++) {
            af[0][ks] = LDA(par, 0, ks);
            af[1][ks] = LDA(par, 1, ks);
            bfa[ks]   = LDB(par, 0, ks);
        }
        if (T + 1 < NT) STAGE_B(nxt, 1, T + 1);
        asm volatile("s_waitcnt lgkmcnt(8)" ::: "memory");
        __builtin_amdgcn_s_barrier();
        asm volatile("s_waitcnt lgkmcnt(0)" ::: "memory");
        __builtin_amdgcn_sched_barrier(0);
        __builtin_amdgcn_s_setprio(1);
        #pragma unroll
        for (int ks = 0; ks < 4; ks++) {
            acc[0][0] = MFMA(af[0][ks], bfa[ks], acc[0][0]);
            acc[1][0] = MFMA(af[1][ks], bfa[ks], acc[1][0]);
        }
        __builtin_amdgcn_s_setprio(0);
        __builtin_amdgcn_sched_barrier(0);
        __builtin_amdgcn_s_barrier();
        // ---------- phase 1: ra*cb (4 ds_reads; stage A0 of T+2) ----------
        #pragma unroll
        for (int ks = 0; ks < 4; ks++) bfb[ks] = LDB(par, 1, ks);
        if (T + 2 < NT) STAGE_A(par, 0, T + 2);   // LA[par][0] last read in p0
        __builtin_amdgcn_s_barrier();
        asm volatile("s_waitcnt lgkmcnt(0)" ::: "memory");
        __builtin_amdgcn_sched_barrier(0);
        __builtin_amdgcn_s_setprio(1);
        #pragma unroll
        for (int ks = 0; ks < 4; ks++) {
            acc[0][1] = MFMA(af[0][ks], bfb[ks], acc[0][1]);
            acc[1][1] = MFMA(af[1][ks], bfb[ks], acc[1][1]);
        }
        __builtin_amdgcn_s_setprio(0);
        __builtin_amdgcn_sched_barrier(0);
        __builtin_amdgcn_s_barrier();
        // ---------- phase 2: rb*cb (8 ds_reads; stage B0 of T+2) ----------
        #pragma unroll
        for (int ks = 0; ks < 4; ks++) {
            af[0][ks] = LDA(par, 2, ks);          // f=2,3 reuse af regs
            af[1][ks] = LDA(par, 3, ks);
        }
        if (T + 2 < NT) STAGE_B(par, 0, T + 2);   // LB[par][0] last read in p0
        __builtin_amdgcn_s_barrier();
        asm volatile("s_waitcnt lgkmcnt(0)" ::: "memory");
        __builtin_amdgcn_sched_barrier(0);
        __builtin_amdgcn_s_setprio(1);
        #pragma unroll
        for (int ks = 0; ks < 4; ks++) {
            acc[2][1] = MFMA(af[0][ks], bfb[ks], acc[2][1]);
            acc[3][1] = MFMA(af[1][ks], bfb[ks], acc[3][1]);
        }
        __builtin_amdgcn_s_setprio(0);
        __builtin_amdgcn_sched_barrier(0);
        __builtin_amdgcn_s_barrier();
        // ---------- phase 3: rb*ca (0 ds_reads; stage A1 of T+2; tile-boundary
        // vmcnt: leave T+2's {A0,B0,A1}=6 loads in flight, everything older
        // (incl. all of tile T+1) landed) ----------
        if (T + 2 < NT) {
            STAGE_A(par, 1, T + 2);               // LA[par][1] last read in p2
            asm volatile("s_waitcnt vmcnt(6)" ::: "memory");
        } else {
            asm volatile("s_waitcnt vmcnt(0)" ::: "memory");  // tail drain
        }
        __builtin_amdgcn_s_barrier();
        __builtin_amdgcn_s_setprio(1);
        #pragma unroll
        for (int ks = 0; ks < 4; ks++) {
            acc[2][0] = MFMA(af[0][ks], bfa[ks], acc[2][0]);
            acc[3][0] = MFMA(af[1][ks], bfa[ks], acc[3][0]);
        }
        __builtin_amdgcn_s_setprio(0);
        __builtin_amdgcn_sched_barrier(0);
        __builtin_amdgcn_s_barrier();
    }

    // ---- epilogue: C/D layout col=lane&31, row=(reg&3)+8*(reg>>2)+4*(lane>>5)
    #pragma unroll
    for (int f = 0; f < 4; f++) {
        #pragma unroll
        for (int g = 0; g < 2; g++) {
            int col   = tileN + (wn << 6) + (g << 5) + r31;
            int rbase = tileM + (wm << 7) + (f << 5) + (kh << 2);
            #pragma unroll
            for (int r = 0; r < 16; r++) {
                int row = rbase + (r & 3) + ((r >> 2) << 3);
                Cb[(size_t)row * N + col] = acc[f][g][r];
            }
        }
    }
}

// ---- row softmax: fp32 in-place + fp16 copy to ws ----
__global__ __launch_bounds__(256) void softmax_rows(float* __restrict__ S,
                                                    f16* __restrict__ Wh) {
    const size_t row = blockIdx.x;
    float* p = S + row * 2048;
    f16* ph = Wh + row * 2048;
    const int tid = threadIdx.x;
    const int lane = tid & 63;
    const int wave = tid >> 6;
    __shared__ float red[8];

    float4 va = ((const float4*)p)[tid];
    float4 vb = ((const float4*)p)[tid + 256];
    float m = fmaxf(fmaxf(fmaxf(va.x, va.y), fmaxf(va.z, va.w)),
                    fmaxf(fmaxf(vb.x, vb.y), fmaxf(vb.z, vb.w)));
    #pragma unroll
    for (int off = 32; off; off >>= 1) m = fmaxf(m, __shfl_xor(m, off));
    if (lane == 0) red[wave] = m;
    __syncthreads();
    m = fmaxf(fmaxf(red[0], red[1]), fmaxf(red[2], red[3]));

    va.x = __expf(va.x - m); va.y = __expf(va.y - m);
    va.z = __expf(va.z - m); va.w = __expf(va.w - m);
    vb.x = __expf(vb.x - m); vb.y = __expf(vb.y - m);
    vb.z = __expf(vb.z - m); vb.w = __expf(vb.w - m);
    float s = va.x + va.y + va.z + va.w + vb.x + vb.y + vb.z + vb.w;
    #pragma unroll
    for (int off = 32; off; off >>= 1) s += __shfl_xor(s, off);
    if (lane == 0) red[4 + wave] = s;
    __syncthreads();
    s = red[4] + red[5] + red[6] + red[7];
    float inv = 1.0f / s;
    va.x *= inv; va.y *= inv; va.z *= inv; va.w *= inv;
    vb.x *= inv; vb.y *= inv; vb.z *= inv; vb.w *= inv;
    ((float4*)p)[tid] = va;
    ((float4*)p)[tid + 256] = vb;
    half4 ha, hb;
    ha[0] = (f16)va.x; ha[1] = (f16)va.y; ha[2] = (f16)va.z; ha[3] = (f16)va.w;
    hb[0] = (f16)vb.x; hb[1] = (f16)vb.y; hb[2] = (f16)vb.z; hb[3] = (f16)vb.w;
    ((half4*)ph)[tid] = ha;
    ((half4*)ph)[tid + 256] = hb;
}

extern "C" void kernel_launch(void* const* d_in, const int* in_sizes, int n_in,
                              void* d_out, int out_size, void* d_ws, size_t ws_size,
                              hipStream_t stream) {
    const float* Q = (const float*)d_in[0];   // [8,2048,1024]
    const float* K = (const float*)d_in[1];   // [8,2048,1024]
    float* ctx = (float*)d_out;               // [8,2048,1024]
    float* W   = (float*)d_out + 16777216;    // [8,2048,2048]

    f16* Qh = (f16*)d_ws;        // 32 MB
    f16* Kh = Qh + 16777216;     // 32 MB
    f16* Kt = Kh + 16777216;     // 32 MB, [B][D][Tk]
    f16* Wh = (f16*)d_ws;        // 64 MB, aliases Qh+Kh (dead after QK GEMM)

    // 1. converts
    cvt_f32_f16<<<16384, 256, 0, stream>>>(Q, Qh, 4194304);
    k_cvt_transpose<<<dim3(16, 32, 8), 256, 0, stream>>>(K, Kh, Kt);

    // 2. scores = Qh @ Kh^T  (M=2048, N=2048, K_=1024) -> W region (raw)
    gemm_bt8<<<dim3(8, 64), 512, 0, stream>>>(
        Qh, Kh, W, 1024, 2048, 8, 2048L * 1024, 2048L * 1024, 2048L * 2048);

    // 3. softmax rows (16384 rows of 2048): fp32 in place + fp16 -> Wh
    softmax_rows<<<16384, 256, 0, stream>>>(W, Wh);

    // 4. context = Wh @ Kt^T  (M=2048, N=1024, K_=2048)
    gemm_bt8<<<dim3(8, 32), 512, 0, stream>>>(
        Wh, Kt, ctx, 2048, 1024, 4, 2048L * 2048, 1024L * 2048, 2048L * 1024);
}

// Round 2
// 472.756 us; speedup vs baseline: 1.0151x; 1.0084x over previous
//
#include <hip/hip_runtime.h>

// Problem: B=8, Tq=2048, Tk=2048, D=1024 (all fp32 in/out)
//   scores  = Q @ K^T            [B,Tq,Tk]
//   weights = softmax(scores)    (output 1, at d_out + 16777216)
//   context = weights @ K        (output 0, at d_out)
//
// ws layout (96 MB):
//   phase 1:  Qh f16 [B][Tq][D] @ 0       (32 MB)
//             Kh f16 [B][Tk][D] @ 32 MB   (32 MB)
//             Kt f16 [B][D][Tk] @ 64 MB   (32 MB)
//   phase 2 (after QK GEMM, Qh/Kh dead):
//             Wh f16 [B][Tq][Tk] @ 0      (64 MB)   <- written by softmax
//
// GEMM: 256x256 tile, 8 waves (2Mx4N), BK=64, 32x32x16 f16 MFMA, 4-phase
// per-K-tile schedule with counted vmcnt(6). THIS ROUND: fragment loads are
// inline-asm ds_read_b128 on precomputed LDS byte addresses (hipcc cannot
// prove the async global_load_lds writes don't alias the C++ LDS reads of
// LA[par][h] with runtime par/h, and may insert conservative vmcnt(0) drains
// -> m218 drain-0 behavior ~900 TF; asm reads remove that), plus flattened
// named-register fragments to stay under the 256-VGPR/8-wave cap.

typedef _Float16 f16;
typedef _Float16 half4 __attribute__((ext_vector_type(4)));
typedef _Float16 half8 __attribute__((ext_vector_type(8)));
typedef float floatx16 __attribute__((ext_vector_type(16)));

__device__ __forceinline__ void gl2lds16(const void* g, void* l) {
    __builtin_amdgcn_global_load_lds(
        (const __attribute__((address_space(1))) unsigned int*)g,
        (__attribute__((address_space(3))) unsigned int*)l,
        16, 0, 0);
}

__device__ __forceinline__ unsigned lds_off(const void* p) {
    return (unsigned)(unsigned long long)
        (const __attribute__((address_space(3))) void*)p;
}

__device__ __forceinline__ half8 dsr(unsigned a) {
    half8 r;
    asm volatile("ds_read_b128 %0, %1" : "=v"(r) : "v"(a));
    return r;
}

#define MFMA(a, b, c) __builtin_amdgcn_mfma_f32_32x32x16_f16((a), (b), (c), 0, 0, 0)
#define WAIT_LGKM0() asm volatile("s_waitcnt lgkmcnt(0)" ::: "memory")
#define WAIT_LGKM8() asm volatile("s_waitcnt lgkmcnt(8)" ::: "memory")
#define WAIT_VM6()   asm volatile("s_waitcnt vmcnt(6)" ::: "memory")
#define WAIT_VM0()   asm volatile("s_waitcnt vmcnt(0)" ::: "memory")
#define SBAR()       __builtin_amdgcn_s_barrier()
#define SCHED0()     __builtin_amdgcn_sched_barrier(0)

// ---- fp32 -> fp16 convert ----
__global__ __launch_bounds__(256) void cvt_f32_f16(const float* __restrict__ src,
                                                   f16* __restrict__ dst, int n4) {
    int i = blockIdx.x * 256 + threadIdx.x;
    if (i >= n4) return;
    float4 v = ((const float4*)src)[i];
    half4 h;
    h[0] = (f16)v.x; h[1] = (f16)v.y; h[2] = (f16)v.z; h[3] = (f16)v.w;
    ((half4*)dst)[i] = h;
}

// ---- K: fp32 -> fp16 row-major copy + transposed copy (64x64 tiles) ----
__global__ __launch_bounds__(256) void k_cvt_transpose(const float* __restrict__ K,
                                                       f16* __restrict__ Kh,
                                                       f16* __restrict__ Kt) {
    __shared__ f16 tile[64][72];                  // +8 f16 pad
    const int b  = blockIdx.z;
    const int k0 = blockIdx.y * 64;               // Tk tile
    const int d0 = blockIdx.x * 64;               // D tile
    const float* src = K + (size_t)b * 2048 * 1024;
    f16* khb = Kh + (size_t)b * 2048 * 1024;
    f16* ktb = Kt + (size_t)b * 1024 * 2048;
    const int r  = threadIdx.x >> 4;              // 0..15
    const int c4 = (threadIdx.x & 15) * 4;        // 0..60
    #pragma unroll
    for (int it = 0; it < 4; it++) {
        int kr = it * 16 + r;
        float4 v = *(const float4*)&src[(size_t)(k0 + kr) * 1024 + d0 + c4];
        half4 h;
        h[0] = (f16)v.x; h[1] = (f16)v.y; h[2] = (f16)v.z; h[3] = (f16)v.w;
        *(half4*)&khb[(size_t)(k0 + kr) * 1024 + d0 + c4] = h;
        *(half4*)&tile[kr][c4] = h;
    }
    __syncthreads();
    #pragma unroll
    for (int it = 0; it < 4; it++) {
        int dr = it * 16 + r;
        half4 h;
        h[0] = tile[c4 + 0][dr]; h[1] = tile[c4 + 1][dr];
        h[2] = tile[c4 + 2][dr]; h[3] = tile[c4 + 3][dr];
        *(half4*)&ktb[(size_t)(d0 + dr) * 2048 + k0 + c4] = h;
    }
}

// ---- 8-phase 256x256 bt-GEMM: C[M,N] = A[M,K_] * B[N,K_]^T, fp32 out ----
// grid dim3(8, nM*nN), x = batch -> XCD. 512 threads = 8 waves (2M x 4N).
__global__ __launch_bounds__(512, 2) void gemm_bt8(const f16* __restrict__ Amat,
                                                   const f16* __restrict__ Bmat,
                                                   float* __restrict__ C,
                                                   int K_, int N, int nN,
                                                   long sA, long sB, long sC) {
    // [parity][half-region][128 rows x 64 f16] ; 64 KB + 64 KB = 128 KiB
    __shared__ __align__(16) f16 LA[2][2][8192];
    __shared__ __align__(16) f16 LB[2][2][8192];
    const int tid  = threadIdx.x;
    const int lane = tid & 63;
    const int wave = tid >> 6;                    // 0..7
    const int wm   = wave >> 2;                   // 0..1 (row strip of 128)
    const int wn   = wave & 3;                    // 0..3 (col strip of 64)
    const int bz   = blockIdx.x;                  // batch -> XCD
    const int tileM = (blockIdx.y / nN) * 256;
    const int tileN = (blockIdx.y % nN) * 256;
    const f16* Ab = Amat + (size_t)bz * sA;
    const f16* Bb = Bmat + (size_t)bz * sB;
    float* Cb = C + (size_t)bz * sC;
    const int NT = K_ >> 6;                       // K-tiles of 64
    const size_t g2 = (size_t)128 * K_;           // 2nd gl2lds source offset

    // staging: thread t -> chunks t, t+512 of a 16KB half-tile; chunk c:
    // lds_row = c>>3, cc = c&7, global k-chunk = cc ^ (lds_row&7).
    const int r0  = tid >> 3;
    const int gcc = (tid & 7) ^ (r0 & 7);
    const f16* sAp = Ab + (size_t)(tileM + r0) * K_ + gcc * 8;
    const f16* sBp = Bb + (size_t)(tileN + (r0 & 31) + (r0 >> 5) * 64) * K_ + gcc * 8;

    // read-side
    const int r31 = lane & 31;
    const int kh  = lane >> 5;
    const int sw  = lane & 7;
    const unsigned baseA0 = lds_off(&LA[0][0][0]) + (unsigned)((r31 + (wm << 6)) * 128);
    const unsigned baseB0 = lds_off(&LB[0][0][0]) + (unsigned)(((wn << 5) + r31) * 128);
    const unsigned pc0 = (unsigned)(((0 + kh) ^ sw) << 4);
    const unsigned pc1 = (unsigned)(((2 + kh) ^ sw) << 4);
    const unsigned pc2 = (unsigned)(((4 + kh) ^ sw) << 4);
    const unsigned pc3 = (unsigned)(((6 + kh) ^ sw) << 4);

    floatx16 acc00 = {0.f}, acc01 = {0.f}, acc10 = {0.f}, acc11 = {0.f};
    floatx16 acc20 = {0.f}, acc21 = {0.f}, acc30 = {0.f}, acc31 = {0.f};
    #pragma unroll
    for (int r = 0; r < 16; r++) {
        acc00[r] = 0.f; acc01[r] = 0.f; acc10[r] = 0.f; acc11[r] = 0.f;
        acc20[r] = 0.f; acc21[r] = 0.f; acc30[r] = 0.f; acc31[r] = 0.f;
    }

#define STAGE_A(P, H, SRC) do { const f16* _s = (SRC); f16* _d = &LA[P][H][tid * 8]; \
        gl2lds16(_s, _d); gl2lds16(_s + g2, _d + 4096); } while (0)
#define STAGE_B(P, H, SRC) do { const f16* _s = (SRC); f16* _d = &LB[P][H][tid * 8]; \
        gl2lds16(_s, _d); gl2lds16(_s + g2, _d + 4096); } while (0)

    // prologue: tile0 {A0,B0,A1,B1} (8 loads) then tile1 {A0,B0,A1} (6 loads);
    // vmcnt(6): tile0 fully landed, tile1's 3 half-tiles in flight.
    STAGE_A(0, 0, sAp);
    STAGE_B(0, 0, sBp);
    STAGE_A(0, 1, sAp + (size_t)64 * K_);
    STAGE_B(0, 1, sBp + (size_t)32 * K_);
    STAGE_A(1, 0, sAp + 64);
    STAGE_B(1, 0, sBp + 64);
    STAGE_A(1, 1, sAp + (size_t)64 * K_ + 64);
    WAIT_VM6();
    SBAR();

    const f16* gB1 = sBp + (size_t)32 * K_ + 64;  // B1(T+1) source
    const f16* gA0 = sAp + 128;                   // A0(T+2)
    const f16* gB0 = sBp + 128;                   // B0(T+2)
    const f16* gA1 = sAp + (size_t)64 * K_ + 128; // A1(T+2)

    for (int T = 0; T < NT; ++T) {
        const int par = T & 1;
        const unsigned bA = baseA0 + (unsigned)(par << 15);
        const unsigned bB = baseB0 + (unsigned)(par << 15);

        // ---------- phase 0: ra*ca (12 asm ds_reads; stage B1 of T+1) -------
        half8 a00 = dsr(bA + pc0),        a01 = dsr(bA + pc1);
        half8 a02 = dsr(bA + pc2),        a03 = dsr(bA + pc3);
        half8 a10 = dsr(bA + 4096 + pc0), a11 = dsr(bA + 4096 + pc1);
        half8 a12 = dsr(bA + 4096 + pc2), a13 = dsr(bA + 4096 + pc3);
        half8 b00 = dsr(bB + pc0),        b01 = dsr(bB + pc1);
        half8 b02 = dsr(bB + pc2),        b03 = dsr(bB + pc3);
        if (T + 1 < NT) STAGE_B(par ^ 1, 1, gB1);
        WAIT_LGKM8();
        SBAR();
        WAIT_LGKM0();
        SCHED0();
        __builtin_amdgcn_s_setprio(1);
        acc00 = MFMA(a00, b00, acc00); acc10 = MFMA(a10, b00, acc10);
        acc00 = MFMA(a01, b01, acc00); acc10 = MFMA(a11, b01, acc10);
        acc00 = MFMA(a02, b02, acc00); acc10 = MFMA(a12, b02, acc10);
        acc00 = MFMA(a03, b03, acc00); acc10 = MFMA(a13, b03, acc10);
        __builtin_amdgcn_s_setprio(0);
        SCHED0();
        SBAR();
        // ---------- phase 1: ra*cb (4 ds_reads; stage A0 of T+2) ------------
        half8 b10 = dsr(bB + 16384 + pc0), b11 = dsr(bB + 16384 + pc1);
        half8 b12 = dsr(bB + 16384 + pc2), b13 = dsr(bB + 16384 + pc3);
        if (T + 2 < NT) STAGE_A(par, 0, gA0);     // LA[par][0] last read in p0
        SBAR();
        WAIT_LGKM0();
        SCHED0();
        __builtin_amdgcn_s_setprio(1);
        acc01 = MFMA(a00, b10, acc01); acc11 = MFMA(a10, b10, acc11);
        acc01 = MFMA(a01, b11, acc01); acc11 = MFMA(a11, b11, acc11);
        acc01 = MFMA(a02, b12, acc01); acc11 = MFMA(a12, b12, acc11);
        acc01 = MFMA(a03, b13, acc01); acc11 = MFMA(a13, b13, acc11);
        __builtin_amdgcn_s_setprio(0);
        SCHED0();
        SBAR();
        // ---------- phase 2: rb*cb (8 ds_reads; stage B0 of T+2) ------------
        half8 a20 = dsr(bA + 16384 + pc0),        a21 = dsr(bA + 16384 + pc1);
        half8 a22 = dsr(bA + 16384 + pc2),        a23 = dsr(bA + 16384 + pc3);
        half8 a30 = dsr(bA + 20480 + pc0),        a31 = dsr(bA + 20480 + pc1);
        half8 a32 = dsr(bA + 20480 + pc2),        a33 = dsr(bA + 20480 + pc3);
        if (T + 2 < NT) STAGE_B(par, 0, gB0);     // LB[par][0] last read in p0
        SBAR();
        WAIT_LGKM0();
        SCHED0();
        __builtin_amdgcn_s_setprio(1);
        acc21 = MFMA(a20, b10, acc21); acc31 = MFMA(a30, b10, acc31);
        acc21 = MFMA(a21, b11, acc21); acc31 = MFMA(a31, b11, acc31);
        acc21 = MFMA(a22, b12, acc21); acc31 = MFMA(a32, b12, acc31);
        acc21 = MFMA(a23, b13, acc21); acc31 = MFMA(a33, b13, acc31);
        __builtin_amdgcn_s_setprio(0);
        SCHED0();
        SBAR();
        // ---------- phase 3: rb*ca (0 ds_reads; stage A1 of T+2; tile-
        // boundary vmcnt(6): T+2's {A0,B0,A1} stay in flight, older landed) --
        if (T + 2 < NT) {
            STAGE_A(par, 1, gA1);                 // LA[par][1] last read in p2
            WAIT_VM6();
        } else {
            WAIT_VM0();                           // tail drain
        }
        SBAR();
        SCHED0();
        __builtin_amdgcn_s_setprio(1);
        acc20 = MFMA(a20, b00, acc20); acc30 = MFMA(a30, b00, acc30);
        acc20 = MFMA(a21, b01, acc20); acc30 = MFMA(a31, b01, acc30);
        acc20 = MFMA(a22, b02, acc20); acc30 = MFMA(a32, b02, acc30);
        acc20 = MFMA(a23, b03, acc20); acc30 = MFMA(a33, b03, acc30);
        __builtin_amdgcn_s_setprio(0);
        SCHED0();
        SBAR();
        gB1 += 64; gA0 += 64; gB0 += 64; gA1 += 64;
    }

    // epilogue: C/D layout col=lane&31, row=(reg&3)+8*(reg>>2)+4*(lane>>5)
#define EPI(ACC, F, G) do { \
        int col   = tileN + (wn << 6) + ((G) << 5) + r31; \
        int rbase = tileM + (wm << 7) + ((F) << 5) + (kh << 2); \
        _Pragma("unroll") \
        for (int r = 0; r < 16; r++) { \
            int row = rbase + (r & 3) + ((r >> 2) << 3); \
            Cb[(size_t)row * N + col] = ACC[r]; \
        } } while (0)
    EPI(acc00, 0, 0); EPI(acc01, 0, 1);
    EPI(acc10, 1, 0); EPI(acc11, 1, 1);
    EPI(acc20, 2, 0); EPI(acc21, 2, 1);
    EPI(acc30, 3, 0); EPI(acc31, 3, 1);
#undef EPI
#undef STAGE_A
#undef STAGE_B
}

// ---- row softmax: fp32 in-place + fp16 copy to ws ----
__global__ __launch_bounds__(256) void softmax_rows(float* __restrict__ S,
                                                    f16* __restrict__ Wh) {
    const size_t row = blockIdx.x;
    float* p = S + row * 2048;
    f16* ph = Wh + row * 2048;
    const int tid = threadIdx.x;
    const int lane = tid & 63;
    const int wave = tid >> 6;
    __shared__ float red[8];

    float4 va = ((const float4*)p)[tid];
    float4 vb = ((const float4*)p)[tid + 256];
    float m = fmaxf(fmaxf(fmaxf(va.x, va.y), fmaxf(va.z, va.w)),
                    fmaxf(fmaxf(vb.x, vb.y), fmaxf(vb.z, vb.w)));
    #pragma unroll
    for (int off = 32; off; off >>= 1) m = fmaxf(m, __shfl_xor(m, off));
    if (lane == 0) red[wave] = m;
    __syncthreads();
    m = fmaxf(fmaxf(red[0], red[1]), fmaxf(red[2], red[3]));

    va.x = __expf(va.x - m); va.y = __expf(va.y - m);
    va.z = __expf(va.z - m); va.w = __expf(va.w - m);
    vb.x = __expf(vb.x - m); vb.y = __expf(vb.y - m);
    vb.z = __expf(vb.z - m); vb.w = __expf(vb.w - m);
    float s = va.x + va.y + va.z + va.w + vb.x + vb.y + vb.z + vb.w;
    #pragma unroll
    for (int off = 32; off; off >>= 1) s += __shfl_xor(s, off);
    if (lane == 0) red[4 + wave] = s;
    __syncthreads();
    s = red[4] + red[5] + red[6] + red[7];
    float inv = 1.0f / s;
    va.x *= inv; va.y *= inv; va.z *= inv; va.w *= inv;
    vb.x *= inv; vb.y *= inv; vb.z *= inv; vb.w *= inv;
    ((float4*)p)[tid] = va;
    ((float4*)p)[tid + 256] = vb;
    half4 ha, hb;
    ha[0] = (f16)va.x; ha[1] = (f16)va.y; ha[2] = (f16)va.z; ha[3] = (f16)va.w;
    hb[0] = (f16)vb.x; hb[1] = (f16)vb.y; hb[2] = (f16)vb.z; hb[3] = (f16)vb.w;
    ((half4*)ph)[tid] = ha;
    ((half4*)ph)[tid + 256] = hb;
}

extern "C" void kernel_launch(void* const* d_in, const int* in_sizes, int n_in,
                              void* d_out, int out_size, void* d_ws, size_t ws_size,
                              hipStream_t stream) {
    const float* Q = (const float*)d_in[0];   // [8,2048,1024]
    const float* K = (const float*)d_in[1];   // [8,2048,1024]
    float* ctx = (float*)d_out;               // [8,2048,1024]
    float* W   = (float*)d_out + 16777216;    // [8,2048,2048]

    f16* Qh = (f16*)d_ws;        // 32 MB
    f16* Kh = Qh + 16777216;     // 32 MB
    f16* Kt = Kh + 16777216;     // 32 MB, [B][D][Tk]
    f16* Wh = (f16*)d_ws;        // 64 MB, aliases Qh+Kh (dead after QK GEMM)

    // 1. converts
    cvt_f32_f16<<<16384, 256, 0, stream>>>(Q, Qh, 4194304);
    k_cvt_transpose<<<dim3(16, 32, 8), 256, 0, stream>>>(K, Kh, Kt);

    // 2. scores = Qh @ Kh^T  (M=2048, N=2048, K_=1024) -> W region (raw)
    gemm_bt8<<<dim3(8, 64), 512, 0, stream>>>(
        Qh, Kh, W, 1024, 2048, 8, 2048L * 1024, 2048L * 1024, 2048L * 2048);

    // 3. softmax rows (16384 rows of 2048): fp32 in place + fp16 -> Wh
    softmax_rows<<<16384, 256, 0, stream>>>(W, Wh);

    // 4. context = Wh @ Kt^T  (M=2048, N=1024, K_=2048)
    gemm_bt8<<<dim3(8, 32), 512, 0, stream>>>(
        Wh, Kt, ctx, 2048, 1024, 4, 2048L * 2048, 1024L * 2048, 2048L * 1024);
}